// Round 1
// baseline (3523.436 us; speedup 1.0000x reference)
//
#include <hip/hip_runtime.h>
#include <math.h>

// ---------------- problem constants ----------------
#define T_LEN   1024
#define HIDDEN  2048
#define NUMV    16
#define NUMK    8
#define HKD     128
#define QKVZ_N  6144   // 2*KEY_DIM + 2*VALUE_DIM
#define KEY_DIM 1024
#define VAL_DIM 2048

__device__ __forceinline__ float sigmoidf_(float x) { return 1.f / (1.f + expf(-x)); }

// ---------------------------------------------------------------------------
// GEMM: C[M,N] = A[M,K] * B[N,K]^T   (both row-major, K contiguous)
// 64x64 tile, K-tile 16, 4x4 per thread, fp32.
// LDS stored transposed As[k][m] (pad 68 keeps ds_read_b128 16B-aligned).
// ---------------------------------------------------------------------------
__global__ __launch_bounds__(256) void gemm_bt(const float* __restrict__ A,
                                               const float* __restrict__ B,
                                               float* __restrict__ C,
                                               int M, int N, int K) {
    __shared__ float As[16][68];
    __shared__ float Bs[16][68];
    const int tid = threadIdx.x;
    const int m0 = blockIdx.y * 64;
    const int n0 = blockIdx.x * 64;
    const int tx = tid & 15;        // n micro
    const int ty = tid >> 4;        // m micro
    const int lr = tid >> 2;        // 0..63 tile row for staging
    const int lk = (tid & 3) << 2;  // 0,4,8,12 k offset for staging

    float acc[4][4];
#pragma unroll
    for (int i = 0; i < 4; ++i)
#pragma unroll
        for (int j = 0; j < 4; ++j) acc[i][j] = 0.f;

    for (int k0 = 0; k0 < K; k0 += 16) {
        float4 av = *(const float4*)(A + (size_t)(m0 + lr) * K + k0 + lk);
        float4 bv = make_float4(0.f, 0.f, 0.f, 0.f);
        if (n0 + lr < N) bv = *(const float4*)(B + (size_t)(n0 + lr) * K + k0 + lk);
        __syncthreads();
        As[lk + 0][lr] = av.x; As[lk + 1][lr] = av.y; As[lk + 2][lr] = av.z; As[lk + 3][lr] = av.w;
        Bs[lk + 0][lr] = bv.x; Bs[lk + 1][lr] = bv.y; Bs[lk + 2][lr] = bv.z; Bs[lk + 3][lr] = bv.w;
        __syncthreads();
#pragma unroll
        for (int kk = 0; kk < 16; ++kk) {
            float4 a4 = *(const float4*)&As[kk][ty << 2];
            float4 b4 = *(const float4*)&Bs[kk][tx << 2];
            const float ar[4] = {a4.x, a4.y, a4.z, a4.w};
            const float br[4] = {b4.x, b4.y, b4.z, b4.w};
#pragma unroll
            for (int i = 0; i < 4; ++i)
#pragma unroll
                for (int j = 0; j < 4; ++j) acc[i][j] = fmaf(ar[i], br[j], acc[i][j]);
        }
    }
#pragma unroll
    for (int i = 0; i < 4; ++i) {
        const int row = m0 + (ty << 2) + i;
        const int col = n0 + (tx << 2);
        if (col + 3 < N) {
            *(float4*)(C + (size_t)row * N + col) =
                make_float4(acc[i][0], acc[i][1], acc[i][2], acc[i][3]);
        } else {
#pragma unroll
            for (int j = 0; j < 4; ++j)
                if (col + j < N) C[(size_t)row * N + col + j] = acc[i][j];
        }
    }
}

// ---------------------------------------------------------------------------
// Depthwise causal conv1d (K=4) + SiLU over mixed [q|k|v] channel layout.
// qkvz row layout per k-head block of 768: [q 128 | k 128 | v 256 | z 256]
// ---------------------------------------------------------------------------
__global__ __launch_bounds__(256) void conv_silu(const float* __restrict__ qkvz,
                                                 const float* __restrict__ conv_w,
                                                 float* __restrict__ qc,
                                                 float* __restrict__ kc,
                                                 float* __restrict__ vc) {
    const int idx = blockIdx.x * 256 + threadIdx.x;  // T_LEN*4096 threads
    const int t = idx >> 12;
    const int c = idx & 4095;
    int col;
    float* dst;
    if (c < 1024) {            // q
        col = ((c >> 7) * 768) + (c & 127);
        dst = qc + t * 1024 + c;
    } else if (c < 2048) {     // k
        const int cc = c - 1024;
        col = ((cc >> 7) * 768) + 128 + (cc & 127);
        dst = kc + t * 1024 + cc;
    } else {                   // v
        const int cc = c - 2048;
        col = ((cc >> 8) * 768) + 256 + (cc & 255);
        dst = vc + t * 2048 + cc;
    }
    const float w0 = conv_w[c * 4 + 0];
    const float w1 = conv_w[c * 4 + 1];
    const float w2 = conv_w[c * 4 + 2];
    const float w3 = conv_w[c * 4 + 3];
    float acc = qkvz[(size_t)t * QKVZ_N + col] * w3;
    if (t >= 1) acc = fmaf(qkvz[(size_t)(t - 1) * QKVZ_N + col], w2, acc);
    if (t >= 2) acc = fmaf(qkvz[(size_t)(t - 2) * QKVZ_N + col], w1, acc);
    if (t >= 3) acc = fmaf(qkvz[(size_t)(t - 3) * QKVZ_N + col], w0, acc);
    *dst = acc * sigmoidf_(acc);  // silu
}

// ---------------------------------------------------------------------------
// L2 normalize q and k per (t, k-head); fold scale=HK^-0.5 into q.
// grid: T_LEN*16 blocks (first 8 = q heads, next 8 = k heads), 64 threads.
// ---------------------------------------------------------------------------
__global__ __launch_bounds__(64) void l2norm_qk(float* __restrict__ qc, float* __restrict__ kc) {
    const int b = blockIdx.x;
    const int t = b >> 4;
    const int hh = b & 15;
    float* p;
    float extra;
    if (hh < 8) { p = qc + t * 1024 + hh * 128; extra = 0.08838834764831845f; }  // 128^-0.5
    else        { p = kc + t * 1024 + (hh - 8) * 128; extra = 1.f; }
    const int j = threadIdx.x * 2;
    float2 x = *(const float2*)(p + j);
    float ss = x.x * x.x + x.y * x.y;
#pragma unroll
    for (int m = 1; m < 64; m <<= 1) ss += __shfl_xor(ss, m, 64);
    const float r = rsqrtf(ss + 1e-6f) * extra;
    *(float2*)(p + j) = make_float2(x.x * r, x.y * r);
}

// ---------------------------------------------------------------------------
// Gates: beta = sigmoid(b); decay = exp(-exp(A_log)*softplus(a + dt_bias))
// ba layout [T, 8, 4] = [b r0, b r1, a r0, a r1] per k-head
// ---------------------------------------------------------------------------
__global__ __launch_bounds__(256) void gates(const float* __restrict__ ba,
                                             const float* __restrict__ dt_bias,
                                             const float* __restrict__ A_log,
                                             float* __restrict__ dec,
                                             float* __restrict__ bet) {
    const int i = blockIdx.x * 256 + threadIdx.x;  // T_LEN*16
    const int t = i >> 4;
    const int vh = i & 15;
    const int kh = vh >> 1;
    const int r = vh & 1;
    const float b = ba[t * 32 + kh * 4 + r];
    const float a = ba[t * 32 + kh * 4 + 2 + r];
    bet[i] = 1.f / (1.f + expf(-b));
    const float x = a + dt_bias[vh];
    const float sp = (x > 0.f) ? (x + log1pf(expf(-x))) : log1pf(expf(x));
    dec[i] = expf(-expf(A_log[vh]) * sp);
}

// ---------------------------------------------------------------------------
// Gated delta-rule recurrence. 16 blocks (1/value-head) x 256 threads.
// thread: v = tid&127, kg = tid>>7 (wave-uniform -> scalar k/q loads).
// State S[k][v]: each thread holds 64 k-rows of its column in registers.
// ---------------------------------------------------------------------------
__global__ __launch_bounds__(256, 1) void recur(const float* __restrict__ qc,
                                                const float* __restrict__ kc,
                                                const float* __restrict__ vc,
                                                const float* __restrict__ dec,
                                                const float* __restrict__ bet,
                                                float* __restrict__ o) {
    const int h = blockIdx.x;
    const int kh = h >> 1;
    const int tid = threadIdx.x;
    const int v = tid & 127;
    const int kg = __builtin_amdgcn_readfirstlane(tid >> 7);  // wave-uniform
    const float* kb = kc + kh * 128 + kg * 64;
    const float* qb = qc + kh * 128 + kg * 64;
    const float* vb = vc + h * 128;

    float S[64];
#pragma unroll
    for (int j = 0; j < 64; ++j) S[j] = 0.f;

    __shared__ float red1[2][128];
    __shared__ float red2[2][128];

    for (int t = 0; t < T_LEN; ++t) {
        const float d = dec[t * 16 + h];
        const float be = bet[t * 16 + h];
        const float vt = vb[(size_t)t * 2048 + v];

        const float4* k4 = (const float4*)(kb + (size_t)t * 1024);
        float4 kr[16];
#pragma unroll
        for (int i = 0; i < 16; ++i) kr[i] = k4[i];

        float kv0 = 0.f, kv1 = 0.f, kv2 = 0.f, kv3 = 0.f;
#pragma unroll
        for (int i = 0; i < 16; ++i) {
            kv0 = fmaf(kr[i].x, S[4 * i + 0], kv0);
            kv1 = fmaf(kr[i].y, S[4 * i + 1], kv1);
            kv2 = fmaf(kr[i].z, S[4 * i + 2], kv2);
            kv3 = fmaf(kr[i].w, S[4 * i + 3], kv3);
        }
        red1[kg][v] = ((kv0 + kv1) + (kv2 + kv3)) * d;  // k · (decayed S)
        __syncthreads();
        const float delta = (vt - (red1[0][v] + red1[1][v])) * be;

        const float4* q4 = (const float4*)(qb + (size_t)t * 1024);
        float o0 = 0.f, o1 = 0.f, o2 = 0.f, o3 = 0.f;
#pragma unroll
        for (int i = 0; i < 16; ++i) {
            const float4 qv = q4[i];
            S[4 * i + 0] = fmaf(S[4 * i + 0], d, kr[i].x * delta); o0 = fmaf(qv.x, S[4 * i + 0], o0);
            S[4 * i + 1] = fmaf(S[4 * i + 1], d, kr[i].y * delta); o1 = fmaf(qv.y, S[4 * i + 1], o1);
            S[4 * i + 2] = fmaf(S[4 * i + 2], d, kr[i].z * delta); o2 = fmaf(qv.z, S[4 * i + 2], o2);
            S[4 * i + 3] = fmaf(S[4 * i + 3], d, kr[i].w * delta); o3 = fmaf(qv.w, S[4 * i + 3], o3);
        }
        red2[kg][v] = (o0 + o1) + (o2 + o3);
        __syncthreads();
        if (kg == 0) o[(size_t)t * 2048 + h * 128 + v] = red2[0][v] + red2[1][v];
        // next iteration's red1 write is safe: all red1 reads precede the sync above
    }
}

// ---------------------------------------------------------------------------
// Gated RMSNorm: xf = o * silu(z); xn = xf * rsqrt(mean(xf^2)+eps) * w
// z read in place from qkvz (offset 512 within each 768 k-head block).
// ---------------------------------------------------------------------------
__global__ __launch_bounds__(64) void gated_norm(const float* __restrict__ o,
                                                 const float* __restrict__ qkvz,
                                                 const float* __restrict__ nw,
                                                 float* __restrict__ xn) {
    const int b = blockIdx.x;
    const int t = b >> 4;
    const int vh = b & 15;
    const int kh = vh >> 1;
    const int r = vh & 1;
    const float* op = o + (size_t)t * 2048 + vh * 128;
    const float* zp = qkvz + (size_t)t * QKVZ_N + kh * 768 + 512 + r * 128;
    const int j = threadIdx.x * 2;
    const float2 ov = *(const float2*)(op + j);
    const float2 zv = *(const float2*)(zp + j);
    const float f0 = ov.x * zv.x / (1.f + expf(-zv.x));
    const float f1 = ov.y * zv.y / (1.f + expf(-zv.y));
    float ss = f0 * f0 + f1 * f1;
#pragma unroll
    for (int m = 1; m < 64; m <<= 1) ss += __shfl_xor(ss, m, 64);
    const float rs = rsqrtf(ss * (1.f / 128.f) + 1e-6f);
    float* xp = xn + (size_t)t * 2048 + vh * 128;
    *(float2*)(xp + j) = make_float2(f0 * rs * nw[j], f1 * rs * nw[j + 1]);
}

// ---------------------------------------------------------------------------
extern "C" void kernel_launch(void* const* d_in, const int* in_sizes, int n_in,
                              void* d_out, int out_size, void* d_ws, size_t ws_size,
                              hipStream_t stream) {
    const float* hidden  = (const float*)d_in[0];
    const float* w_qkvz  = (const float*)d_in[1];
    const float* w_ba    = (const float*)d_in[2];
    const float* conv_w  = (const float*)d_in[3];
    const float* dt_bias = (const float*)d_in[4];
    const float* A_log   = (const float*)d_in[5];
    const float* norm_w  = (const float*)d_in[6];
    const float* w_out   = (const float*)d_in[7];
    float* out = (float*)d_out;

    // workspace layout (floats); total ~14.75M floats = 56.25 MB
    float* ws   = (float*)d_ws;
    float* qkvz = ws;                  // 1024*6144
    float* ba   = qkvz + 6291456;      // 1024*32
    float* qc   = ba + 32768;          // 1024*1024
    float* kc   = qc + 1048576;        // 1024*1024
    float* vc   = kc + 1048576;        // 1024*2048
    float* dcy  = vc + 2097152;        // 1024*16
    float* bet  = dcy + 16384;         // 1024*16
    float* o    = bet + 16384;         // 1024*2048
    float* xn   = o + 2097152;         // 1024*2048

    gemm_bt<<<dim3(QKVZ_N / 64, T_LEN / 64), 256, 0, stream>>>(hidden, w_qkvz, qkvz,
                                                               T_LEN, QKVZ_N, HIDDEN);
    gemm_bt<<<dim3(1, T_LEN / 64), 256, 0, stream>>>(hidden, w_ba, ba, T_LEN, 32, HIDDEN);
    conv_silu<<<(T_LEN * 4096) / 256, 256, 0, stream>>>(qkvz, conv_w, qc, kc, vc);
    l2norm_qk<<<T_LEN * 16, 64, 0, stream>>>(qc, kc);
    gates<<<(T_LEN * 16) / 256, 256, 0, stream>>>(ba, dt_bias, A_log, dcy, bet);
    recur<<<16, 256, 0, stream>>>(qc, kc, vc, dcy, bet, o);
    gated_norm<<<T_LEN * 16, 64, 0, stream>>>(o, qkvz, norm_w, xn);
    gemm_bt<<<dim3(VAL_DIM / 64, T_LEN / 64), 256, 0, stream>>>(xn, w_out, out,
                                                                T_LEN, VAL_DIM, HIDDEN);
}

// Round 2
// 1417.662 us; speedup vs baseline: 2.4854x; 2.4854x over previous
//
#include <hip/hip_runtime.h>
#include <math.h>

// ---------------- problem constants ----------------
#define T_LEN   1024
#define HIDDEN  2048
#define NUMV    16
#define NUMK    8
#define HKD     128
#define QKVZ_N  6144   // 2*KEY_DIM + 2*VALUE_DIM
#define KEY_DIM 1024
#define VAL_DIM 2048

__device__ __forceinline__ float sigmoidf_(float x) { return 1.f / (1.f + expf(-x)); }

// ---------------------------------------------------------------------------
// GEMM: C[M,N] = A[M,K] * B[N,K]^T   (both row-major, K contiguous)
// 64x64 tile, K-tile 16, 4x4 per thread, fp32.
// ---------------------------------------------------------------------------
__global__ __launch_bounds__(256) void gemm_bt(const float* __restrict__ A,
                                               const float* __restrict__ B,
                                               float* __restrict__ C,
                                               int M, int N, int K) {
    __shared__ float As[16][68];
    __shared__ float Bs[16][68];
    const int tid = threadIdx.x;
    const int m0 = blockIdx.y * 64;
    const int n0 = blockIdx.x * 64;
    const int tx = tid & 15;        // n micro
    const int ty = tid >> 4;        // m micro
    const int lr = tid >> 2;        // 0..63 tile row for staging
    const int lk = (tid & 3) << 2;  // 0,4,8,12 k offset for staging

    float acc[4][4];
#pragma unroll
    for (int i = 0; i < 4; ++i)
#pragma unroll
        for (int j = 0; j < 4; ++j) acc[i][j] = 0.f;

    for (int k0 = 0; k0 < K; k0 += 16) {
        float4 av = *(const float4*)(A + (size_t)(m0 + lr) * K + k0 + lk);
        float4 bv = make_float4(0.f, 0.f, 0.f, 0.f);
        if (n0 + lr < N) bv = *(const float4*)(B + (size_t)(n0 + lr) * K + k0 + lk);
        __syncthreads();
        As[lk + 0][lr] = av.x; As[lk + 1][lr] = av.y; As[lk + 2][lr] = av.z; As[lk + 3][lr] = av.w;
        Bs[lk + 0][lr] = bv.x; Bs[lk + 1][lr] = bv.y; Bs[lk + 2][lr] = bv.z; Bs[lk + 3][lr] = bv.w;
        __syncthreads();
#pragma unroll
        for (int kk = 0; kk < 16; ++kk) {
            float4 a4 = *(const float4*)&As[kk][ty << 2];
            float4 b4 = *(const float4*)&Bs[kk][tx << 2];
            const float ar[4] = {a4.x, a4.y, a4.z, a4.w};
            const float br[4] = {b4.x, b4.y, b4.z, b4.w};
#pragma unroll
            for (int i = 0; i < 4; ++i)
#pragma unroll
                for (int j = 0; j < 4; ++j) acc[i][j] = fmaf(ar[i], br[j], acc[i][j]);
        }
    }
#pragma unroll
    for (int i = 0; i < 4; ++i) {
        const int row = m0 + (ty << 2) + i;
        const int col = n0 + (tx << 2);
        if (col + 3 < N) {
            *(float4*)(C + (size_t)row * N + col) =
                make_float4(acc[i][0], acc[i][1], acc[i][2], acc[i][3]);
        } else {
#pragma unroll
            for (int j = 0; j < 4; ++j)
                if (col + j < N) C[(size_t)row * N + col + j] = acc[i][j];
        }
    }
}

// ---------------------------------------------------------------------------
// Depthwise causal conv1d (K=4) + SiLU over mixed [q|k|v] channel layout.
// qkvz row layout per k-head block of 768: [q 128 | k 128 | v 256 | z 256]
// ---------------------------------------------------------------------------
__global__ __launch_bounds__(256) void conv_silu(const float* __restrict__ qkvz,
                                                 const float* __restrict__ conv_w,
                                                 float* __restrict__ qc,
                                                 float* __restrict__ kc,
                                                 float* __restrict__ vc) {
    const int idx = blockIdx.x * 256 + threadIdx.x;  // T_LEN*4096 threads
    const int t = idx >> 12;
    const int c = idx & 4095;
    int col;
    float* dst;
    if (c < 1024) {            // q
        col = ((c >> 7) * 768) + (c & 127);
        dst = qc + t * 1024 + c;
    } else if (c < 2048) {     // k
        const int cc = c - 1024;
        col = ((cc >> 7) * 768) + 128 + (cc & 127);
        dst = kc + t * 1024 + cc;
    } else {                   // v
        const int cc = c - 2048;
        col = ((cc >> 8) * 768) + 256 + (cc & 255);
        dst = vc + t * 2048 + cc;
    }
    const float w0 = conv_w[c * 4 + 0];
    const float w1 = conv_w[c * 4 + 1];
    const float w2 = conv_w[c * 4 + 2];
    const float w3 = conv_w[c * 4 + 3];
    float acc = qkvz[(size_t)t * QKVZ_N + col] * w3;
    if (t >= 1) acc = fmaf(qkvz[(size_t)(t - 1) * QKVZ_N + col], w2, acc);
    if (t >= 2) acc = fmaf(qkvz[(size_t)(t - 2) * QKVZ_N + col], w1, acc);
    if (t >= 3) acc = fmaf(qkvz[(size_t)(t - 3) * QKVZ_N + col], w0, acc);
    *dst = acc * sigmoidf_(acc);  // silu
}

// ---------------------------------------------------------------------------
// L2 normalize q and k per (t, k-head); fold scale=HK^-0.5 into q.
// ---------------------------------------------------------------------------
__global__ __launch_bounds__(64) void l2norm_qk(float* __restrict__ qc, float* __restrict__ kc) {
    const int b = blockIdx.x;
    const int t = b >> 4;
    const int hh = b & 15;
    float* p;
    float extra;
    if (hh < 8) { p = qc + t * 1024 + hh * 128; extra = 0.08838834764831845f; }  // 128^-0.5
    else        { p = kc + t * 1024 + (hh - 8) * 128; extra = 1.f; }
    const int j = threadIdx.x * 2;
    float2 x = *(const float2*)(p + j);
    float ss = x.x * x.x + x.y * x.y;
#pragma unroll
    for (int m = 1; m < 64; m <<= 1) ss += __shfl_xor(ss, m, 64);
    const float r = rsqrtf(ss + 1e-6f) * extra;
    *(float2*)(p + j) = make_float2(x.x * r, x.y * r);
}

// ---------------------------------------------------------------------------
// Gates: beta = sigmoid(b); decay = exp(-exp(A_log)*softplus(a + dt_bias))
// ---------------------------------------------------------------------------
__global__ __launch_bounds__(256) void gates(const float* __restrict__ ba,
                                             const float* __restrict__ dt_bias,
                                             const float* __restrict__ A_log,
                                             float* __restrict__ dec,
                                             float* __restrict__ bet) {
    const int i = blockIdx.x * 256 + threadIdx.x;  // T_LEN*16
    const int t = i >> 4;
    const int vh = i & 15;
    const int kh = vh >> 1;
    const int r = vh & 1;
    const float b = ba[t * 32 + kh * 4 + r];
    const float a = ba[t * 32 + kh * 4 + 2 + r];
    bet[i] = 1.f / (1.f + expf(-b));
    const float x = a + dt_bias[vh];
    const float sp = (x > 0.f) ? (x + log1pf(expf(-x))) : log1pf(expf(x));
    dec[i] = expf(-expf(A_log[vh]) * sp);
}

// ---------------------------------------------------------------------------
// Gated delta-rule recurrence, v2: barrier-free, shuffle-reduced, prefetched.
//
// 256 blocks x 64 threads (1 wave/block, ~1 wave/CU).
//   block b: head h = b>>4, v-group vg = b&15 (8 v-columns per block)
//   lane l:  kg = l>>3 (8-way k split, 16 rows each), vi = l&7 (column)
// Each lane holds S[rows kg*16..+16][column vg*8+vi] = 16 regs.
// Per step: per-lane 16-FMA partial kv -> shfl_xor{8,16,32} full reduction
// (all cross-k comms in-wave; no LDS, no __syncthreads).
// Loads software-pipelined with 2 ping-pong buffers (distance ~2 steps).
// ---------------------------------------------------------------------------
__global__ __launch_bounds__(64) void recur(const float* __restrict__ qc,
                                            const float* __restrict__ kc,
                                            const float* __restrict__ vc,
                                            const float* __restrict__ dec,
                                            const float* __restrict__ bet,
                                            float* __restrict__ o) {
    const int b = blockIdx.x;
    const int h = b >> 4;        // value head 0..15
    const int vg = b & 15;       // v-group 0..15
    const int kh = h >> 1;       // key head
    const int lane = threadIdx.x;
    const int kg = lane >> 3;    // 0..7  (k rows kg*16..kg*16+16)
    const int vi = lane & 7;     // column within group
    const int v = vg * 8 + vi;   // 0..127

    const float* kbase = kc + kh * 128 + kg * 16;
    const float* qbase = qc + kh * 128 + kg * 16;
    const float* vbase = vc + h * 128 + v;
    const float* dbase = dec + h;
    const float* bbase = bet + h;
    float* obase = o + h * 128 + v;

    float S[16];
#pragma unroll
    for (int j = 0; j < 16; ++j) S[j] = 0.f;

    float4 KA[4], QA[4], KB[4], QB[4];
    float VA, DA, BA_, VB, DB, BB_;

    auto issue = [&](float4 (&K)[4], float4 (&Q)[4], float& V, float& D, float& Bt,
                     int t) {
        const float4* kp = (const float4*)(kbase + (size_t)t * 1024);
        const float4* qp = (const float4*)(qbase + (size_t)t * 1024);
        K[0] = kp[0]; K[1] = kp[1]; K[2] = kp[2]; K[3] = kp[3];
        Q[0] = qp[0]; Q[1] = qp[1]; Q[2] = qp[2]; Q[3] = qp[3];
        V = vbase[(size_t)t * 2048];
        D = dbase[(size_t)t * 16];
        Bt = bbase[(size_t)t * 16];
    };

    auto compute = [&](const float4 (&K)[4], const float4 (&Q)[4], float V, float D,
                       float Bt, int t) {
        // kv partial over this lane's 16 rows (4 independent chains)
        float c0 = 0.f, c1 = 0.f, c2 = 0.f, c3 = 0.f;
#pragma unroll
        for (int i = 0; i < 4; ++i) {
            c0 = fmaf(K[i].x, S[4 * i + 0], c0);
            c1 = fmaf(K[i].y, S[4 * i + 1], c1);
            c2 = fmaf(K[i].z, S[4 * i + 2], c2);
            c3 = fmaf(K[i].w, S[4 * i + 3], c3);
        }
        float kv = (c0 + c1) + (c2 + c3);
        kv += __shfl_xor(kv, 8, 64);
        kv += __shfl_xor(kv, 16, 64);
        kv += __shfl_xor(kv, 32, 64);   // full k.S for column v, in every lane
        const float delta = (V - D * kv) * Bt;
        float o0 = 0.f, o1 = 0.f, o2 = 0.f, o3 = 0.f;
#pragma unroll
        for (int i = 0; i < 4; ++i) {
            S[4 * i + 0] = fmaf(S[4 * i + 0], D, K[i].x * delta); o0 = fmaf(Q[i].x, S[4 * i + 0], o0);
            S[4 * i + 1] = fmaf(S[4 * i + 1], D, K[i].y * delta); o1 = fmaf(Q[i].y, S[4 * i + 1], o1);
            S[4 * i + 2] = fmaf(S[4 * i + 2], D, K[i].z * delta); o2 = fmaf(Q[i].z, S[4 * i + 2], o2);
            S[4 * i + 3] = fmaf(S[4 * i + 3], D, K[i].w * delta); o3 = fmaf(Q[i].w, S[4 * i + 3], o3);
        }
        float oo = (o0 + o1) + (o2 + o3);
        oo += __shfl_xor(oo, 8, 64);
        oo += __shfl_xor(oo, 16, 64);
        oo += __shfl_xor(oo, 32, 64);
        if (kg == 0) obase[(size_t)t * 2048] = oo;
    };

    issue(KA, QA, VA, DA, BA_, 0);
    issue(KB, QB, VB, DB, BB_, 1);
    for (int t = 0; t < T_LEN; t += 2) {
        compute(KA, QA, VA, DA, BA_, t);
        {
            const int tn = (t + 2 < T_LEN) ? t + 2 : T_LEN - 1;
            issue(KA, QA, VA, DA, BA_, tn);
        }
        compute(KB, QB, VB, DB, BB_, t + 1);
        {
            const int tn = (t + 3 < T_LEN) ? t + 3 : T_LEN - 1;
            issue(KB, QB, VB, DB, BB_, tn);
        }
    }
}

// ---------------------------------------------------------------------------
// Gated RMSNorm: xf = o * silu(z); xn = xf * rsqrt(mean(xf^2)+eps) * w
// ---------------------------------------------------------------------------
__global__ __launch_bounds__(64) void gated_norm(const float* __restrict__ o,
                                                 const float* __restrict__ qkvz,
                                                 const float* __restrict__ nw,
                                                 float* __restrict__ xn) {
    const int b = blockIdx.x;
    const int t = b >> 4;
    const int vh = b & 15;
    const int kh = vh >> 1;
    const int r = vh & 1;
    const float* op = o + (size_t)t * 2048 + vh * 128;
    const float* zp = qkvz + (size_t)t * QKVZ_N + kh * 768 + 512 + r * 128;
    const int j = threadIdx.x * 2;
    const float2 ov = *(const float2*)(op + j);
    const float2 zv = *(const float2*)(zp + j);
    const float f0 = ov.x * zv.x / (1.f + expf(-zv.x));
    const float f1 = ov.y * zv.y / (1.f + expf(-zv.y));
    float ss = f0 * f0 + f1 * f1;
#pragma unroll
    for (int m = 1; m < 64; m <<= 1) ss += __shfl_xor(ss, m, 64);
    const float rs = rsqrtf(ss * (1.f / 128.f) + 1e-6f);
    float* xp = xn + (size_t)t * 2048 + vh * 128;
    *(float2*)(xp + j) = make_float2(f0 * rs * nw[j], f1 * rs * nw[j + 1]);
}

// ---------------------------------------------------------------------------
extern "C" void kernel_launch(void* const* d_in, const int* in_sizes, int n_in,
                              void* d_out, int out_size, void* d_ws, size_t ws_size,
                              hipStream_t stream) {
    const float* hidden  = (const float*)d_in[0];
    const float* w_qkvz  = (const float*)d_in[1];
    const float* w_ba    = (const float*)d_in[2];
    const float* conv_w  = (const float*)d_in[3];
    const float* dt_bias = (const float*)d_in[4];
    const float* A_log   = (const float*)d_in[5];
    const float* norm_w  = (const float*)d_in[6];
    const float* w_out   = (const float*)d_in[7];
    float* out = (float*)d_out;

    float* ws   = (float*)d_ws;
    float* qkvz = ws;                  // 1024*6144
    float* ba   = qkvz + 6291456;      // 1024*32
    float* qc   = ba + 32768;          // 1024*1024
    float* kc   = qc + 1048576;        // 1024*1024
    float* vc   = kc + 1048576;        // 1024*2048
    float* dcy  = vc + 2097152;        // 1024*16
    float* bet  = dcy + 16384;         // 1024*16
    float* o    = bet + 16384;         // 1024*2048
    float* xn   = o + 2097152;         // 1024*2048

    gemm_bt<<<dim3(QKVZ_N / 64, T_LEN / 64), 256, 0, stream>>>(hidden, w_qkvz, qkvz,
                                                               T_LEN, QKVZ_N, HIDDEN);
    gemm_bt<<<dim3(1, T_LEN / 64), 256, 0, stream>>>(hidden, w_ba, ba, T_LEN, 32, HIDDEN);
    conv_silu<<<(T_LEN * 4096) / 256, 256, 0, stream>>>(qkvz, conv_w, qc, kc, vc);
    l2norm_qk<<<T_LEN * 16, 64, 0, stream>>>(qc, kc);
    gates<<<(T_LEN * 16) / 256, 256, 0, stream>>>(ba, dt_bias, A_log, dcy, bet);
    recur<<<256, 64, 0, stream>>>(qc, kc, vc, dcy, bet, o);
    gated_norm<<<T_LEN * 16, 64, 0, stream>>>(o, qkvz, norm_w, xn);
    gemm_bt<<<dim3(VAL_DIM / 64, T_LEN / 64), 256, 0, stream>>>(xn, w_out, out,
                                                                T_LEN, VAL_DIM, HIDDEN);
}